// Round 2
// baseline (3206.351 us; speedup 1.0000x reference)
//
#include <hip/hip_runtime.h>
#include <math.h>

constexpr int B = 8, C = 128, H = 256, W = 256, NN = 256, KNN = 5;
constexpr int HW = H * W;

// ws float offsets
constexpr int WS_ROWSUM = 0;      // 2048 floats
constexpr int WS_COLSUM = 2048;   // 2048
constexpr int WS_GMUL   = 4096;   // 2048  (1 + gate)
constexpr int WS_SUM    = 6144;   // 128
constexpr int WS_SUMSQ  = 6272;   // 128
constexpr int WS_SCALE  = 6400;   // 128
constexpr int WS_BIAS   = 6528;   // 128
// total 6656 floats = 26,624 B (memset 32 KiB at launch)

// ---------------- xm row sums: rowsum[b,n] = sum_{c,w} x[b,c,n,w] ----------
__global__ void k_rowsum(const float* __restrict__ x, float* __restrict__ ws) {
    const int b = blockIdx.x >> 8;
    const int n = blockIdx.x & 255;
    const int t = threadIdx.x;
    float acc = 0.f;
    const float* p = x + ((size_t)(b * C) * H + n) * W + t;
    for (int c = 0; c < C; ++c) acc += p[(size_t)c * HW];
    __shared__ float red[256];
    red[t] = acc;
    __syncthreads();
    for (int s = 128; s > 0; s >>= 1) {
        if (t < s) red[t] += red[t + s];
        __syncthreads();
    }
    if (t == 0) ws[WS_ROWSUM + b * 256 + n] = red[0];
}

// ---------------- xm col sums: colsum[b,w] = sum_{c,h} x[b,c,h,w] ----------
__global__ void k_colsum(const float* __restrict__ x, float* __restrict__ ws) {
    const int b = blockIdx.x >> 7;
    const int c = blockIdx.x & 127;
    const int t = threadIdx.x;  // column index
    const float* p = x + (size_t)(b * C + c) * HW + t;
    float acc = 0.f;
    for (int h = 0; h < H; ++h) acc += p[(size_t)h * W];
    atomicAdd(&ws[WS_COLSUM + b * 256 + t], acc);
}

// ---------------- gate: sign-KNN top-5, gather, sigmoid --------------------
__global__ void k_gate(float* __restrict__ ws) {
    const int b = blockIdx.x;
    const int i = threadIdx.x;
    __shared__ float xm[256], sgn[256];
    const float v = ws[WS_ROWSUM + b * 256 + i] * (1.f / 32768.f)
                  + ws[WS_COLSUM + b * 256 + i] * (1.f / 32768.f);
    xm[i] = v;
    const float vv = v * 0.5f;
    sgn[i] = vv / fmaxf(fabsf(vv), 1e-12f);
    __syncthreads();
    const float si = sgn[i];
    float bd[KNN];
    int bi[KNN];
    for (int k = 0; k < KNN; ++k) { bd[k] = 1e30f; bi[k] = 0; }
    for (int j = 0; j < NN; ++j) {
        float d = si - sgn[j];
        d *= d;
        if (d < bd[KNN - 1]) {  // strict: equal dist keeps lower index (stable top_k)
            int p = KNN - 1;
            while (p > 0 && bd[p - 1] > d) {
                bd[p] = bd[p - 1];
                bi[p] = bi[p - 1];
                --p;
            }
            bd[p] = d;
            bi[p] = j;
        }
    }
    float gs = 0.f;
    for (int k = 0; k < KNN; ++k) gs += xm[bi[k]];
    const float gate = 1.f / (1.f + expf(-gs));
    ws[WS_GMUL + b * 256 + i] = 1.f + gate;
}

// ---------------- 3x3 conv on y = (1+gate[b,row]) * x ----------------------
// block: 16x16 output pixels x 32 output channels. thread: o = t&31, grp = t>>5
// handles 2 rows x 16 px.
__global__ __launch_bounds__(256) void k_conv3(const float* __restrict__ x,
                                               const float* __restrict__ w1,
                                               const float* __restrict__ ws,
                                               float* __restrict__ hout) {
    const int bx = blockIdx.x;
    const int og = bx & 3;
    const int tile = bx >> 2;
    const int tx = tile & 15;
    const int ty = (tile >> 4) & 15;
    const int b = tile >> 8;
    const int t = threadIdx.x;
    const int o = t & 31;
    const int grp = t >> 5;
    const int oy0 = ty * 16, ox0 = tx * 16;
    const int o0 = og * 32;

    __shared__ float sIn[18 * 20];
    __shared__ float sW[32 * 9];
    __shared__ float gm[18];
    if (t < 18) {
        const int y = oy0 - 1 + t;
        gm[t] = (y >= 0 && y < H) ? ws[WS_GMUL + b * 256 + y] : 0.f;
    }

    float acc[32];
#pragma unroll
    for (int i = 0; i < 32; ++i) acc[i] = 0.f;

    for (int c = 0; c < C; ++c) {
        __syncthreads();  // prev compute done; gm ready on first iter
        // stage 18x18 input tile (row stride 20), pre-multiplied by (1+gate)
        for (int i = t; i < 360; i += 256) {
            const int r = i / 20, cc = i % 20;
            float val = 0.f;
            if (cc < 18) {
                const int y = oy0 - 1 + r, xx = ox0 - 1 + cc;
                if (y >= 0 && y < H && xx >= 0 && xx < W)
                    val = x[((size_t)(b * C + c) * H + y) * W + xx] * gm[r];
            }
            sIn[r * 20 + cc] = val;
        }
        // stage weights for 32 output channels (288 elems, 256 threads -> strided!)
        for (int i = t; i < 288; i += 256) {
            const int oo = i / 9, kk = i % 9;
            sW[oo * 9 + kk] = w1[((size_t)(o0 + oo) * C + c) * 9 + kk];
        }
        __syncthreads();

        float wr[9];
#pragma unroll
        for (int k = 0; k < 9; ++k) wr[k] = sW[o * 9 + k];
#pragma unroll
        for (int rr = 0; rr < 2; ++rr) {
            const int row = grp * 2 + rr;
#pragma unroll
            for (int ky = 0; ky < 3; ++ky) {
                const float* rp = &sIn[(row + ky) * 20];
                float rv[18];
#pragma unroll
                for (int i2 = 0; i2 < 18; ++i2) rv[i2] = rp[i2];
#pragma unroll
                for (int kx = 0; kx < 3; ++kx) {
                    const float wv = wr[ky * 3 + kx];
#pragma unroll
                    for (int xx = 0; xx < 16; ++xx)
                        acc[rr * 16 + xx] = fmaf(rv[xx + kx], wv, acc[rr * 16 + xx]);
                }
            }
        }
    }
#pragma unroll
    for (int rr = 0; rr < 2; ++rr) {
        const int y = oy0 + grp * 2 + rr;
        float* op = hout + ((size_t)(b * C + o0 + o) * H + y) * W + ox0;
#pragma unroll
        for (int xx = 0; xx < 16; ++xx) op[xx] = acc[rr * 16 + xx];
    }
}

// ---------------- BN stats over h (stored in d_out) ------------------------
__global__ void k_stats(const float* __restrict__ hbuf, float* __restrict__ ws) {
    const int b = blockIdx.x >> 7;
    const int c = blockIdx.x & 127;
    const int t = threadIdx.x;
    const float4* p4 = (const float4*)(hbuf + (size_t)(b * C + c) * HW);
    float s = 0.f, s2 = 0.f;
    for (int i = t; i < HW / 4; i += 256) {
        const float4 v = p4[i];
        s += v.x + v.y + v.z + v.w;
        s2 = fmaf(v.x, v.x, s2);
        s2 = fmaf(v.y, v.y, s2);
        s2 = fmaf(v.z, v.z, s2);
        s2 = fmaf(v.w, v.w, s2);
    }
    __shared__ float rs[256], rs2[256];
    rs[t] = s;
    rs2[t] = s2;
    __syncthreads();
    for (int k = 128; k > 0; k >>= 1) {
        if (t < k) {
            rs[t] += rs[t + k];
            rs2[t] += rs2[t + k];
        }
        __syncthreads();
    }
    if (t == 0) {
        atomicAdd(&ws[WS_SUM + c], rs[0]);
        atomicAdd(&ws[WS_SUMSQ + c], rs2[0]);
    }
}

__global__ void k_scalebias(const float* __restrict__ gamma,
                            const float* __restrict__ beta, float* __restrict__ ws) {
    const int c = threadIdx.x;
    const float cnt = (float)B * HW;
    const float mu = ws[WS_SUM + c] / cnt;
    const float var = ws[WS_SUMSQ + c] / cnt - mu * mu;
    const float rs = rsqrtf(var + 1e-5f);
    const float sc = rs * gamma[c];
    ws[WS_SCALE + c] = sc;
    ws[WS_BIAS + c] = beta[c] - mu * sc;
}

// ---------------- BN apply + ReLU + 1x1 conv, in place on d_out ------------
// block owns 64 pixels of batch b across ALL channels: reads them, overwrites them.
__global__ __launch_bounds__(256) void k_conv1(float* __restrict__ io,
                                               const float* __restrict__ w2,
                                               const float* __restrict__ ws) {
    const int bx = blockIdx.x;
    const int b = bx >> 10;
    const int pb = bx & 1023;
    const int t = threadIdx.x;
    const int o = t & 127;
    const int half = t >> 7;
    const int px0 = half * 32;
    __shared__ float hb[C][64];
    __shared__ float w2s[C][33];

    float* iobase = io + (size_t)b * C * HW + pb * 64;
    for (int i = t; i < C * 64; i += 256) {
        const int c = i >> 6, p = i & 63;
        const float v = iobase[(size_t)c * HW + p];
        hb[c][p] = fmaxf(fmaf(v, ws[WS_SCALE + c], ws[WS_BIAS + c]), 0.f);
    }

    float acc[32];
#pragma unroll
    for (int i = 0; i < 32; ++i) acc[i] = 0.f;

    for (int cg = 0; cg < 4; ++cg) {
        __syncthreads();  // prev compute done (and hb staged for cg==0)
        for (int i = t; i < C * 32; i += 256) {
            const int oo = i >> 5, cc2 = i & 31;
            w2s[oo][cc2] = w2[oo * C + cg * 32 + cc2];
        }
        __syncthreads();
        for (int cc2 = 0; cc2 < 32; ++cc2) {
            const int c = cg * 32 + cc2;
            const float wv = w2s[o][cc2];
#pragma unroll
            for (int p4 = 0; p4 < 8; ++p4) {
                const float4 h4 = *reinterpret_cast<const float4*>(&hb[c][px0 + p4 * 4]);
                acc[p4 * 4 + 0] = fmaf(h4.x, wv, acc[p4 * 4 + 0]);
                acc[p4 * 4 + 1] = fmaf(h4.y, wv, acc[p4 * 4 + 1]);
                acc[p4 * 4 + 2] = fmaf(h4.z, wv, acc[p4 * 4 + 2]);
                acc[p4 * 4 + 3] = fmaf(h4.w, wv, acc[p4 * 4 + 3]);
            }
        }
    }
    float* op = io + (size_t)(b * C + o) * HW + pb * 64 + px0;
#pragma unroll
    for (int p = 0; p < 32; ++p) op[p] = acc[p];
}

extern "C" void kernel_launch(void* const* d_in, const int* in_sizes, int n_in,
                              void* d_out, int out_size, void* d_ws, size_t ws_size,
                              hipStream_t stream) {
    const float* x = (const float*)d_in[0];
    const float* w1 = (const float*)d_in[1];
    const float* gamma = (const float*)d_in[2];
    const float* beta = (const float*)d_in[3];
    const float* w2 = (const float*)d_in[4];
    float* out = (float*)d_out;
    float* ws = (float*)d_ws;

    hipMemsetAsync(d_ws, 0, 32768, stream);
    k_rowsum<<<B * NN, 256, 0, stream>>>(x, ws);
    k_colsum<<<B * C, 256, 0, stream>>>(x, ws);
    k_gate<<<B, 256, 0, stream>>>(ws);
    k_conv3<<<B * 256 * 4, 256, 0, stream>>>(x, w1, ws, out);
    k_stats<<<B * C, 256, 0, stream>>>(out, ws);
    k_scalebias<<<1, 128, 0, stream>>>(gamma, beta, ws);
    k_conv1<<<B * 1024, 256, 0, stream>>>(out, w2, ws);
}

// Round 3
// 947.881 us; speedup vs baseline: 3.3827x; 3.3827x over previous
//
#include <hip/hip_runtime.h>
#include <hip/hip_bf16.h>
#include <math.h>

constexpr int B = 8, C = 128, H = 256, W = 256, NN = 256, KNN = 5;
constexpr int HW = H * W;

// ws float offsets
constexpr int WS_ROWSUM = 0;      // 2048 floats
constexpr int WS_COLSUM = 2048;   // 2048
constexpr int WS_GMUL   = 4096;   // 2048  (1 + gate)
constexpr int WS_SUM    = 6144;   // 128
constexpr int WS_SUMSQ  = 6272;   // 128
constexpr int WS_SCALE  = 6400;   // 128
constexpr int WS_BIAS   = 6528;   // 128
constexpr int WS_WT     = 8192;   // bf16 weights: 36*128*32 ushort = 294,912 B
// total ws usage: 32 KiB + 288 KiB = 320 KiB

typedef __attribute__((ext_vector_type(8))) short bf16x8;
typedef __attribute__((ext_vector_type(4))) float f32x4;

__device__ inline unsigned short f2bf(float f) {
    __hip_bfloat16 h = __float2bfloat16(f);
    return *reinterpret_cast<unsigned short*>(&h);
}

// ---------------- xm row sums ----------------------------------------------
__global__ void k_rowsum(const float* __restrict__ x, float* __restrict__ ws) {
    const int b = blockIdx.x >> 8;
    const int n = blockIdx.x & 255;
    const int t = threadIdx.x;
    float acc = 0.f;
    const float* p = x + ((size_t)(b * C) * H + n) * W + t;
    for (int c = 0; c < C; ++c) acc += p[(size_t)c * HW];
    __shared__ float red[256];
    red[t] = acc;
    __syncthreads();
    for (int s = 128; s > 0; s >>= 1) {
        if (t < s) red[t] += red[t + s];
        __syncthreads();
    }
    if (t == 0) ws[WS_ROWSUM + b * 256 + n] = red[0];
}

// ---------------- xm col sums ----------------------------------------------
__global__ void k_colsum(const float* __restrict__ x, float* __restrict__ ws) {
    const int b = blockIdx.x >> 7;
    const int c = blockIdx.x & 127;
    const int t = threadIdx.x;
    const float* p = x + (size_t)(b * C + c) * HW + t;
    float acc = 0.f;
    for (int h = 0; h < H; ++h) acc += p[(size_t)h * W];
    atomicAdd(&ws[WS_COLSUM + b * 256 + t], acc);
}

// ---------------- gate -----------------------------------------------------
__global__ void k_gate(float* __restrict__ ws) {
    const int b = blockIdx.x;
    const int i = threadIdx.x;
    __shared__ float xm[256], sgn[256];
    const float v = ws[WS_ROWSUM + b * 256 + i] * (1.f / 32768.f)
                  + ws[WS_COLSUM + b * 256 + i] * (1.f / 32768.f);
    xm[i] = v;
    const float vv = v * 0.5f;
    sgn[i] = vv / fmaxf(fabsf(vv), 1e-12f);
    __syncthreads();
    const float si = sgn[i];
    float bd[KNN];
    int bi[KNN];
    for (int k = 0; k < KNN; ++k) { bd[k] = 1e30f; bi[k] = 0; }
    for (int j = 0; j < NN; ++j) {
        float d = si - sgn[j];
        d *= d;
        if (d < bd[KNN - 1]) {
            int p = KNN - 1;
            while (p > 0 && bd[p - 1] > d) {
                bd[p] = bd[p - 1];
                bi[p] = bi[p - 1];
                --p;
            }
            bd[p] = d;
            bi[p] = j;
        }
    }
    float gs = 0.f;
    for (int k = 0; k < KNN; ++k) gs += xm[bi[k]];
    const float gate = 1.f / (1.f + expf(-gs));
    ws[WS_GMUL + b * 256 + i] = 1.f + gate;
}

// ---------------- weight pre-transform to bf16 [s][och][k] -----------------
// step s (0..35): pos = s>>2 (ky=pos/3, kx=pos%3), channel chunk = (s&3)*32
__global__ void k_wprep(const float* __restrict__ w1, unsigned short* __restrict__ wt) {
    const int e = blockIdx.x * 256 + threadIdx.x;  // 576 blocks * 256 = 147456
    const int j = e & 7;
    const int kg = (e >> 3) & 3;
    const int och = (e >> 5) & 127;
    const int s = e >> 12;
    const int c = (s & 3) * 32 + kg * 8 + j;
    const int pos = s >> 2;
    const int ky = pos / 3, kx = pos - ky * 3;
    wt[e] = f2bf(w1[(((size_t)och * C + c) * 3 + ky) * 3 + kx]);
}

// ---------------- B-tile fetch: 8 channels for (px, kg) at step s ----------
__device__ inline bf16x8 b_fetch(const float* __restrict__ x, int b, int s,
                                 int hrow, int w0, int px, int kg,
                                 float g0, float g1, float g2) {
    const int pos = s >> 2;
    const int ky = pos / 3, kx = pos - ky * 3;
    const int cbase = (s & 3) * 32 + kg * 8;
    int crow = hrow + ky - 1;
    int col = w0 + px + kx - 1;
    const float g = (ky == 0) ? g0 : ((ky == 1) ? g1 : g2);  // 0 if row OOB
    const float sc = ((unsigned)col < (unsigned)W) ? g : 0.f;
    crow = min(max(crow, 0), H - 1);
    col = min(max(col, 0), W - 1);
    const float* p = x + (((size_t)(b * C + cbase) * H + crow) * W + col);
    union { bf16x8 v8; unsigned short u[8]; } r;
#pragma unroll
    for (int j = 0; j < 8; ++j) r.u[j] = f2bf(p[(size_t)j * HW] * sc);
    return r.v8;
}

// ---------------- MFMA 3x3 conv: h = conv3(y), y = (1+gate[row]) * x -------
// block: 128 och x 128 px (one half-row). 4 waves 2x2, each 64x64.
// K = 36 steps of 32 (9 positions x 4 channel chunks).
__global__ __launch_bounds__(256) void k_conv3(const float* __restrict__ x,
                                               const unsigned short* __restrict__ wt,
                                               const float* __restrict__ ws,
                                               float* __restrict__ hout) {
    const int bx = blockIdx.x;
    const int whalf = bx & 1;
    const int hrow = (bx >> 1) & 255;
    const int b = bx >> 9;
    const int w0 = whalf * 128;

    const int t = threadIdx.x;
    const int wv = t >> 6;
    const int l = t & 63;
    const int wm = wv >> 1, wn = wv & 1;
    const int lr = l & 15, lq = l >> 4;

    // padded rows: 40 ushort = 80 B = 5 x 16B slots (slot 4 unused) -> 2-way max on b128
    __shared__ unsigned short sA[128 * 40];  // [och][k(32) + pad]
    __shared__ unsigned short sB[128 * 40];  // [px][k(32) + pad]

    // gate multipliers for the 3 candidate source rows (0 if OOB)
    float g0, g1, g2;
    {
        const int r0 = hrow - 1, r2 = hrow + 1;
        g0 = (r0 >= 0) ? ws[WS_GMUL + b * 256 + r0] : 0.f;
        g1 = ws[WS_GMUL + b * 256 + hrow];
        g2 = (r2 < H) ? ws[WS_GMUL + b * 256 + r2] : 0.f;
    }

    f32x4 acc[4][4];
#pragma unroll
    for (int i = 0; i < 4; ++i)
#pragma unroll
        for (int j = 0; j < 4; ++j) acc[i][j] = (f32x4){0.f, 0.f, 0.f, 0.f};

    // staging roles
    const int a_och = t & 127, a_h = t >> 7;       // A: 32B per thread
    const int b_px = t & 127, b_kg0 = t >> 7;      // B: (px, kg0) and (px, kg0+2)
    const int b_kg1 = b_kg0 + 2;

    // prologue: prefetch s=0
    uint4 pa0, pa1;
    bf16x8 pb0, pb1;
    {
        const uint4* asrc = reinterpret_cast<const uint4*>(wt + (size_t)a_och * 32 + a_h * 16);
        pa0 = asrc[0];
        pa1 = asrc[1];
        pb0 = b_fetch(x, b, 0, hrow, w0, b_px, b_kg0, g0, g1, g2);
        pb1 = b_fetch(x, b, 0, hrow, w0, b_px, b_kg1, g0, g1, g2);
    }

    for (int s = 0; s < 36; ++s) {
        __syncthreads();  // compute on previous tile done
        *reinterpret_cast<uint4*>(&sA[a_och * 40 + a_h * 16]) = pa0;
        *reinterpret_cast<uint4*>(&sA[a_och * 40 + a_h * 16 + 8]) = pa1;
        *reinterpret_cast<bf16x8*>(&sB[b_px * 40 + b_kg0 * 8]) = pb0;
        *reinterpret_cast<bf16x8*>(&sB[b_px * 40 + b_kg1 * 8]) = pb1;
        __syncthreads();  // tile visible

        if (s + 1 < 36) {  // prefetch next step under this step's MFMAs
            const uint4* asrc = reinterpret_cast<const uint4*>(
                wt + (size_t)(s + 1) * 4096 + (size_t)a_och * 32 + a_h * 16);
            pa0 = asrc[0];
            pa1 = asrc[1];
            pb0 = b_fetch(x, b, s + 1, hrow, w0, b_px, b_kg0, g0, g1, g2);
            pb1 = b_fetch(x, b, s + 1, hrow, w0, b_px, b_kg1, g0, g1, g2);
        }

        bf16x8 af[4], bf[4];
#pragma unroll
        for (int mf = 0; mf < 4; ++mf) {
            const int och = wm * 64 + mf * 16 + lr;
            af[mf] = *reinterpret_cast<const bf16x8*>(&sA[och * 40 + lq * 8]);
        }
#pragma unroll
        for (int nf = 0; nf < 4; ++nf) {
            const int px = wn * 64 + nf * 16 + lr;
            bf[nf] = *reinterpret_cast<const bf16x8*>(&sB[px * 40 + lq * 8]);
        }
#pragma unroll
        for (int mf = 0; mf < 4; ++mf)
#pragma unroll
            for (int nf = 0; nf < 4; ++nf)
                acc[mf][nf] = __builtin_amdgcn_mfma_f32_16x16x32_bf16(
                    af[mf], bf[nf], acc[mf][nf], 0, 0, 0);
    }

    // epilogue: D layout col=lane&15, row=(lane>>4)*4+reg (HW-verified m89)
#pragma unroll
    for (int mf = 0; mf < 4; ++mf) {
#pragma unroll
        for (int reg = 0; reg < 4; ++reg) {
            const int och = wm * 64 + mf * 16 + lq * 4 + reg;
            float* orow = hout + (((size_t)(b * C + och) * H + hrow) * W) + w0;
#pragma unroll
            for (int nf = 0; nf < 4; ++nf)
                orow[wn * 64 + nf * 16 + lr] = acc[mf][nf][reg];
        }
    }
}

// ---------------- BN stats over h (stored in d_out) ------------------------
__global__ void k_stats(const float* __restrict__ hbuf, float* __restrict__ ws) {
    const int b = blockIdx.x >> 7;
    const int c = blockIdx.x & 127;
    const int t = threadIdx.x;
    const float4* p4 = (const float4*)(hbuf + (size_t)(b * C + c) * HW);
    float s = 0.f, s2 = 0.f;
    for (int i = t; i < HW / 4; i += 256) {
        const float4 v = p4[i];
        s += v.x + v.y + v.z + v.w;
        s2 = fmaf(v.x, v.x, s2);
        s2 = fmaf(v.y, v.y, s2);
        s2 = fmaf(v.z, v.z, s2);
        s2 = fmaf(v.w, v.w, s2);
    }
    __shared__ float rs[256], rs2[256];
    rs[t] = s;
    rs2[t] = s2;
    __syncthreads();
    for (int k = 128; k > 0; k >>= 1) {
        if (t < k) {
            rs[t] += rs[t + k];
            rs2[t] += rs2[t + k];
        }
        __syncthreads();
    }
    if (t == 0) {
        atomicAdd(&ws[WS_SUM + c], rs[0]);
        atomicAdd(&ws[WS_SUMSQ + c], rs2[0]);
    }
}

__global__ void k_scalebias(const float* __restrict__ gamma,
                            const float* __restrict__ beta, float* __restrict__ ws) {
    const int c = threadIdx.x;
    const float cnt = (float)B * HW;
    const float mu = ws[WS_SUM + c] / cnt;
    const float var = ws[WS_SUMSQ + c] / cnt - mu * mu;
    const float rs = rsqrtf(var + 1e-5f);
    const float sc = rs * gamma[c];
    ws[WS_SCALE + c] = sc;
    ws[WS_BIAS + c] = beta[c] - mu * sc;
}

// ---------------- BN apply + ReLU + 1x1 conv, in place on d_out ------------
__global__ __launch_bounds__(256) void k_conv1(float* __restrict__ io,
                                               const float* __restrict__ w2,
                                               const float* __restrict__ ws) {
    const int bx = blockIdx.x;
    const int b = bx >> 10;
    const int pb = bx & 1023;
    const int t = threadIdx.x;
    const int o = t & 127;
    const int half = t >> 7;
    const int px0 = half * 32;
    __shared__ float hb[C][64];
    __shared__ float w2s[C][33];

    float* iobase = io + (size_t)b * C * HW + pb * 64;
    for (int i = t; i < C * 64; i += 256) {
        const int c = i >> 6, p = i & 63;
        const float v = iobase[(size_t)c * HW + p];
        hb[c][p] = fmaxf(fmaf(v, ws[WS_SCALE + c], ws[WS_BIAS + c]), 0.f);
    }

    float acc[32];
#pragma unroll
    for (int i = 0; i < 32; ++i) acc[i] = 0.f;

    for (int cg = 0; cg < 4; ++cg) {
        __syncthreads();
        for (int i = t; i < C * 32; i += 256) {
            const int oo = i >> 5, cc2 = i & 31;
            w2s[oo][cc2] = w2[oo * C + cg * 32 + cc2];
        }
        __syncthreads();
        for (int cc2 = 0; cc2 < 32; ++cc2) {
            const int c = cg * 32 + cc2;
            const float wv = w2s[o][cc2];
#pragma unroll
            for (int p4 = 0; p4 < 8; ++p4) {
                const float4 h4 = *reinterpret_cast<const float4*>(&hb[c][px0 + p4 * 4]);
                acc[p4 * 4 + 0] = fmaf(h4.x, wv, acc[p4 * 4 + 0]);
                acc[p4 * 4 + 1] = fmaf(h4.y, wv, acc[p4 * 4 + 1]);
                acc[p4 * 4 + 2] = fmaf(h4.z, wv, acc[p4 * 4 + 2]);
                acc[p4 * 4 + 3] = fmaf(h4.w, wv, acc[p4 * 4 + 3]);
            }
        }
    }
    float* op = io + (size_t)(b * C + o) * HW + pb * 64 + px0;
#pragma unroll
    for (int p = 0; p < 32; ++p) op[p] = acc[p];
}

extern "C" void kernel_launch(void* const* d_in, const int* in_sizes, int n_in,
                              void* d_out, int out_size, void* d_ws, size_t ws_size,
                              hipStream_t stream) {
    const float* x = (const float*)d_in[0];
    const float* w1 = (const float*)d_in[1];
    const float* gamma = (const float*)d_in[2];
    const float* beta = (const float*)d_in[3];
    const float* w2 = (const float*)d_in[4];
    float* out = (float*)d_out;
    float* ws = (float*)d_ws;
    unsigned short* wt = (unsigned short*)(ws + WS_WT);

    hipMemsetAsync(d_ws, 0, 32768, stream);
    k_wprep<<<576, 256, 0, stream>>>(w1, wt);
    k_rowsum<<<B * NN, 256, 0, stream>>>(x, ws);
    k_colsum<<<B * C, 256, 0, stream>>>(x, ws);
    k_gate<<<B, 256, 0, stream>>>(ws);
    k_conv3<<<B * 256 * 2, 256, 0, stream>>>(x, wt, ws, out);
    k_stats<<<B * C, 256, 0, stream>>>(out, ws);
    k_scalebias<<<1, 128, 0, stream>>>(gamma, beta, ws);
    k_conv1<<<B * 1024, 256, 0, stream>>>(out, w2, ws);
}

// Round 4
// 697.330 us; speedup vs baseline: 4.5980x; 1.3593x over previous
//
#include <hip/hip_runtime.h>
#include <hip/hip_bf16.h>
#include <math.h>

constexpr int B = 8, C = 128, H = 256, W = 256, NN = 256, KNN = 5;
constexpr int HW = H * W;

// ws float offsets
constexpr int WS_ROWSUM = 0;      // 2048 floats
constexpr int WS_COLSUM = 2048;   // 2048
constexpr int WS_GMUL   = 4096;   // 2048  (1 + gate)
constexpr int WS_SCALE  = 6144;   // 128
constexpr int WS_BIAS   = 6272;   // 128
constexpr int WS_PART   = 8192;   // [128 c][64 slot][2 (sum,sq)] = 16384 floats
constexpr int WS_WT     = 24576;  // conv3 bf16 weights: 36*128*32 ushort = 73728 floats
constexpr int WS_W2T    = 98304;  // conv1 bf16 hi/lo weights: 16*128*32 ushort = 32768 floats
// total 131072 floats = 512 KiB; memset first 98304 B (through WS_PART region)

typedef __attribute__((ext_vector_type(8))) short bf16x8;
typedef __attribute__((ext_vector_type(4))) float f32x4;

__device__ inline unsigned short f2bf(float f) {
    __hip_bfloat16 h = __float2bfloat16(f);
    return *reinterpret_cast<unsigned short*>(&h);
}
__device__ inline float bf2f(unsigned short u) {
    __hip_bfloat16 h = *reinterpret_cast<__hip_bfloat16*>(&u);
    return __bfloat162float(h);
}

// ---------------- fused row+col sums (one pass over x) ---------------------
// block per (b,c) plane; rowsum[b,r] += sum_w plane[r,w]; colsum[b,w] += sum_h
__global__ __launch_bounds__(256) void k_sums(const float* __restrict__ x,
                                              float* __restrict__ ws) {
    const int b = blockIdx.x >> 7;
    const int c = blockIdx.x & 127;
    const int t = threadIdx.x;
    const int wv = t >> 6;
    const float4* p4 = (const float4*)(x + (size_t)(b * C + c) * HW);
    __shared__ float srow[256];
    __shared__ float scol[4][256];
    float ca0 = 0.f, ca1 = 0.f, ca2 = 0.f, ca3 = 0.f;
    for (int it = 0; it < 64; ++it) {
        const float4 v = p4[it * 256 + t];
        ca0 += v.x; ca1 += v.y; ca2 += v.z; ca3 += v.w;
        float s = v.x + v.y + v.z + v.w;
#pragma unroll
        for (int m = 1; m < 64; m <<= 1) s += __shfl_xor(s, m);
        if ((t & 63) == 0) srow[it * 4 + wv] = s;
    }
    const int cb = (t & 63) * 4;
    scol[wv][cb + 0] = ca0;
    scol[wv][cb + 1] = ca1;
    scol[wv][cb + 2] = ca2;
    scol[wv][cb + 3] = ca3;
    __syncthreads();
    atomicAdd(&ws[WS_ROWSUM + b * 256 + t], srow[t]);
    atomicAdd(&ws[WS_COLSUM + b * 256 + t],
              scol[0][t] + scol[1][t] + scol[2][t] + scol[3][t]);
}

// ---------------- gate -----------------------------------------------------
__global__ void k_gate(float* __restrict__ ws) {
    const int b = blockIdx.x;
    const int i = threadIdx.x;
    __shared__ float xm[256], sgn[256];
    const float v = ws[WS_ROWSUM + b * 256 + i] * (1.f / 32768.f)
                  + ws[WS_COLSUM + b * 256 + i] * (1.f / 32768.f);
    xm[i] = v;
    const float vv = v * 0.5f;
    sgn[i] = vv / fmaxf(fabsf(vv), 1e-12f);
    __syncthreads();
    const float si = sgn[i];
    float bd[KNN];
    int bi[KNN];
    for (int k = 0; k < KNN; ++k) { bd[k] = 1e30f; bi[k] = 0; }
    for (int j = 0; j < NN; ++j) {
        float d = si - sgn[j];
        d *= d;
        if (d < bd[KNN - 1]) {
            int p = KNN - 1;
            while (p > 0 && bd[p - 1] > d) {
                bd[p] = bd[p - 1];
                bi[p] = bi[p - 1];
                --p;
            }
            bd[p] = d;
            bi[p] = j;
        }
    }
    float gs = 0.f;
    for (int k = 0; k < KNN; ++k) gs += xm[bi[k]];
    const float gate = 1.f / (1.f + expf(-gs));
    ws[WS_GMUL + b * 256 + i] = 1.f + gate;
}

// ---------------- conv3 weight pre-transform to bf16 [s][och][k] -----------
__global__ void k_wprep(const float* __restrict__ w1, unsigned short* __restrict__ wt) {
    const int e = blockIdx.x * 256 + threadIdx.x;  // 576*256 = 147456
    const int j = e & 7;
    const int kg = (e >> 3) & 3;
    const int och = (e >> 5) & 127;
    const int s = e >> 12;
    const int c = (s & 3) * 32 + kg * 8 + j;
    const int pos = s >> 2;
    const int ky = pos / 3, kx = pos - ky * 3;
    wt[e] = f2bf(w1[(((size_t)och * C + c) * 3 + ky) * 3 + kx]);
}

// ---------------- conv1 weight hi/lo pre-transform [s][och][32] ------------
// k = s*32+kk = 4c+t4; A[och][4c+{0,1}] = w_hi, [4c+{2,3}] = w_lo
__global__ void k_wprep2(const float* __restrict__ w2, unsigned short* __restrict__ w2t) {
    const int e = blockIdx.x * 256 + threadIdx.x;  // 256*256 = 65536
    const int kk = e & 31;
    const int och = (e >> 5) & 127;
    const int s = e >> 12;
    const int k = s * 32 + kk;
    const int c = k >> 2;
    const int t4 = k & 3;
    const float w = w2[och * C + c];
    const unsigned short hi = f2bf(w);
    w2t[e] = (t4 < 2) ? hi : f2bf(w - bf2f(hi));
}

// ---------------- B-tile fetch for conv3 -----------------------------------
__device__ inline bf16x8 b_fetch(const float* __restrict__ x, int b, int s,
                                 int hrow, int w0, int px, int kg,
                                 float g0, float g1, float g2) {
    const int pos = s >> 2;
    const int ky = pos / 3, kx = pos - ky * 3;
    const int cbase = (s & 3) * 32 + kg * 8;
    int crow = hrow + ky - 1;
    int col = w0 + px + kx - 1;
    const float g = (ky == 0) ? g0 : ((ky == 1) ? g1 : g2);
    const float sc = ((unsigned)col < (unsigned)W) ? g : 0.f;
    crow = min(max(crow, 0), H - 1);
    col = min(max(col, 0), W - 1);
    const float* p = x + (((size_t)(b * C + cbase) * H + crow) * W + col);
    union { bf16x8 v8; unsigned short u[8]; } r;
#pragma unroll
    for (int j = 0; j < 8; ++j) r.u[j] = f2bf(p[(size_t)j * HW] * sc);
    return r.v8;
}

// ---------------- MFMA 3x3 conv + fused BN partial stats -------------------
__global__ __launch_bounds__(256) void k_conv3(const float* __restrict__ x,
                                               const unsigned short* __restrict__ wt,
                                               float* __restrict__ ws,
                                               float* __restrict__ hout) {
    const int bx = blockIdx.x;
    const int whalf = bx & 1;
    const int hrow = (bx >> 1) & 255;
    const int b = bx >> 9;
    const int w0 = whalf * 128;

    const int t = threadIdx.x;
    const int wv = t >> 6;
    const int l = t & 63;
    const int wm = wv >> 1, wn = wv & 1;
    const int lr = l & 15, lq = l >> 4;

    __shared__ unsigned short sA[128 * 40];
    __shared__ unsigned short sB[128 * 40];
    __shared__ float sPart[4][128][2];

    float g0, g1, g2;
    {
        const int r0 = hrow - 1, r2 = hrow + 1;
        g0 = (r0 >= 0) ? ws[WS_GMUL + b * 256 + r0] : 0.f;
        g1 = ws[WS_GMUL + b * 256 + hrow];
        g2 = (r2 < H) ? ws[WS_GMUL + b * 256 + r2] : 0.f;
    }

    f32x4 acc[4][4];
#pragma unroll
    for (int i = 0; i < 4; ++i)
#pragma unroll
        for (int j = 0; j < 4; ++j) acc[i][j] = (f32x4){0.f, 0.f, 0.f, 0.f};

    const int a_och = t & 127, a_h = t >> 7;
    const int b_px = t & 127, b_kg0 = t >> 7;
    const int b_kg1 = b_kg0 + 2;

    uint4 pa0, pa1;
    bf16x8 pb0, pb1;
    {
        const uint4* asrc = reinterpret_cast<const uint4*>(wt + (size_t)a_och * 32 + a_h * 16);
        pa0 = asrc[0];
        pa1 = asrc[1];
        pb0 = b_fetch(x, b, 0, hrow, w0, b_px, b_kg0, g0, g1, g2);
        pb1 = b_fetch(x, b, 0, hrow, w0, b_px, b_kg1, g0, g1, g2);
    }

    for (int s = 0; s < 36; ++s) {
        __syncthreads();
        *reinterpret_cast<uint4*>(&sA[a_och * 40 + a_h * 16]) = pa0;
        *reinterpret_cast<uint4*>(&sA[a_och * 40 + a_h * 16 + 8]) = pa1;
        *reinterpret_cast<bf16x8*>(&sB[b_px * 40 + b_kg0 * 8]) = pb0;
        *reinterpret_cast<bf16x8*>(&sB[b_px * 40 + b_kg1 * 8]) = pb1;
        __syncthreads();

        if (s + 1 < 36) {
            const uint4* asrc = reinterpret_cast<const uint4*>(
                wt + (size_t)(s + 1) * 4096 + (size_t)a_och * 32 + a_h * 16);
            pa0 = asrc[0];
            pa1 = asrc[1];
            pb0 = b_fetch(x, b, s + 1, hrow, w0, b_px, b_kg0, g0, g1, g2);
            pb1 = b_fetch(x, b, s + 1, hrow, w0, b_px, b_kg1, g0, g1, g2);
        }

        bf16x8 af[4], bfr[4];
#pragma unroll
        for (int mf = 0; mf < 4; ++mf) {
            const int och = wm * 64 + mf * 16 + lr;
            af[mf] = *reinterpret_cast<const bf16x8*>(&sA[och * 40 + lq * 8]);
        }
#pragma unroll
        for (int nf = 0; nf < 4; ++nf) {
            const int px = wn * 64 + nf * 16 + lr;
            bfr[nf] = *reinterpret_cast<const bf16x8*>(&sB[px * 40 + lq * 8]);
        }
#pragma unroll
        for (int mf = 0; mf < 4; ++mf)
#pragma unroll
            for (int nf = 0; nf < 4; ++nf)
                acc[mf][nf] = __builtin_amdgcn_mfma_f32_16x16x32_bf16(
                    af[mf], bfr[nf], acc[mf][nf], 0, 0, 0);
    }

    // store h
#pragma unroll
    for (int mf = 0; mf < 4; ++mf) {
#pragma unroll
        for (int reg = 0; reg < 4; ++reg) {
            const int och = wm * 64 + mf * 16 + lq * 4 + reg;
            float* orow = hout + (((size_t)(b * C + och) * H + hrow) * W) + w0;
#pragma unroll
            for (int nf = 0; nf < 4; ++nf)
                orow[wn * 64 + nf * 16 + lr] = acc[mf][nf][reg];
        }
    }

    // fused BN partial stats: per och, sum & sumsq over this block's 128 px
#pragma unroll
    for (int mf = 0; mf < 4; ++mf) {
#pragma unroll
        for (int reg = 0; reg < 4; ++reg) {
            float s = 0.f, q = 0.f;
#pragma unroll
            for (int nf = 0; nf < 4; ++nf) {
                const float v = acc[mf][nf][reg];
                s += v;
                q = fmaf(v, v, q);
            }
#pragma unroll
            for (int m = 1; m < 16; m <<= 1) {
                s += __shfl_xor(s, m);
                q += __shfl_xor(q, m);
            }
            if (lr == 0) {
                const int och = wm * 64 + mf * 16 + lq * 4 + reg;
                sPart[wv][och][0] = s;
                sPart[wv][och][1] = q;
            }
        }
    }
    __syncthreads();
    {
        const int o = t & 127;
        const int which = t >> 7;
        const int wmn = o >> 6;
        const float v = sPart[wmn * 2][o][which] + sPart[wmn * 2 + 1][o][which];
        atomicAdd(&ws[WS_PART + o * 128 + (bx & 63) * 2 + which], v);
    }
}

// ---------------- BN scale/bias from partials ------------------------------
__global__ void k_scalebias(const float* __restrict__ gamma,
                            const float* __restrict__ beta, float* __restrict__ ws) {
    const int c = threadIdx.x;
    const float* p = ws + WS_PART + c * 128;
    float s = 0.f, q = 0.f;
    for (int i = 0; i < 64; ++i) {
        s += p[i * 2];
        q += p[i * 2 + 1];
    }
    const float cnt = (float)B * HW;
    const float mu = s / cnt;
    const float var = q / cnt - mu * mu;
    const float rs = rsqrtf(var + 1e-5f);
    const float sc = rs * gamma[c];
    ws[WS_SCALE + c] = sc;
    ws[WS_BIAS + c] = beta[c] - mu * sc;
}

// ---------------- MFMA conv1: out = W2 * relu(bn(h)), in place on d_out ----
// block: 128 och x 256 px, K_eff = 512 (hi/lo split, exact product).
__global__ __launch_bounds__(256) void k_conv1m(float* __restrict__ io,
                                                const unsigned short* __restrict__ w2t,
                                                const float* __restrict__ ws) {
    const int bx = blockIdx.x;
    const int pblk = bx & 255;
    const int b = bx >> 8;
    const size_t px0 = (size_t)pblk * 256;

    const int t = threadIdx.x;
    const int wv = t >> 6;
    const int l = t & 63;
    const int wm = wv >> 1, wn = wv & 1;
    const int lr = l & 15, lq = l >> 4;

    __shared__ unsigned short sA[128 * 40];
    __shared__ unsigned short sB[256 * 40];
    __shared__ float sSB[128][2];
    if (t < 128) {
        sSB[t][0] = ws[WS_SCALE + t];
        sSB[t][1] = ws[WS_BIAS + t];
    }
    __syncthreads();

    f32x4 acc[4][8];
#pragma unroll
    for (int i = 0; i < 4; ++i)
#pragma unroll
        for (int j = 0; j < 8; ++j) acc[i][j] = (f32x4){0.f, 0.f, 0.f, 0.f};

    const int a_och = t & 127, a_h = t >> 7;
    const float* hbase = io + (size_t)b * C * HW + px0 + t;

    uint4 pa0, pa1;
    union PB { unsigned short u[32]; uint4 q[4]; };
    PB pb;

    auto fetchB = [&](int s, PB& out) {
        const int c0 = s * 8;
#pragma unroll
        for (int j = 0; j < 8; ++j) {
            const float hv = hbase[(size_t)(c0 + j) * HW];
            const float v = fmaxf(fmaf(hv, sSB[c0 + j][0], sSB[c0 + j][1]), 0.f);
            const unsigned short hi = f2bf(v);
            const unsigned short lo = f2bf(v - bf2f(hi));
            out.u[4 * j + 0] = hi;
            out.u[4 * j + 1] = lo;
            out.u[4 * j + 2] = hi;
            out.u[4 * j + 3] = lo;
        }
    };

    {
        const uint4* asrc = reinterpret_cast<const uint4*>(w2t + (size_t)a_och * 32 + a_h * 16);
        pa0 = asrc[0];
        pa1 = asrc[1];
        fetchB(0, pb);
    }

    for (int s = 0; s < 16; ++s) {
        __syncthreads();
        *reinterpret_cast<uint4*>(&sA[a_och * 40 + a_h * 16]) = pa0;
        *reinterpret_cast<uint4*>(&sA[a_och * 40 + a_h * 16 + 8]) = pa1;
#pragma unroll
        for (int qi = 0; qi < 4; ++qi)
            *reinterpret_cast<uint4*>(&sB[t * 40 + qi * 8]) = pb.q[qi];
        __syncthreads();

        if (s + 1 < 16) {
            const uint4* asrc = reinterpret_cast<const uint4*>(
                w2t + (size_t)(s + 1) * 4096 + (size_t)a_och * 32 + a_h * 16);
            pa0 = asrc[0];
            pa1 = asrc[1];
            fetchB(s + 1, pb);
        }

        bf16x8 af[4], bfr[8];
#pragma unroll
        for (int mf = 0; mf < 4; ++mf) {
            const int och = wm * 64 + mf * 16 + lr;
            af[mf] = *reinterpret_cast<const bf16x8*>(&sA[och * 40 + lq * 8]);
        }
#pragma unroll
        for (int nf = 0; nf < 8; ++nf) {
            const int px = wn * 128 + nf * 16 + lr;
            bfr[nf] = *reinterpret_cast<const bf16x8*>(&sB[px * 40 + lq * 8]);
        }
#pragma unroll
        for (int mf = 0; mf < 4; ++mf)
#pragma unroll
            for (int nf = 0; nf < 8; ++nf)
                acc[mf][nf] = __builtin_amdgcn_mfma_f32_16x16x32_bf16(
                    af[mf], bfr[nf], acc[mf][nf], 0, 0, 0);
    }

#pragma unroll
    for (int mf = 0; mf < 4; ++mf) {
#pragma unroll
        for (int reg = 0; reg < 4; ++reg) {
            const int och = wm * 64 + mf * 16 + lq * 4 + reg;
            float* orow = io + (size_t)(b * C + och) * HW + px0;
#pragma unroll
            for (int nf = 0; nf < 8; ++nf)
                orow[wn * 128 + nf * 16 + lr] = acc[mf][nf][reg];
        }
    }
}

extern "C" void kernel_launch(void* const* d_in, const int* in_sizes, int n_in,
                              void* d_out, int out_size, void* d_ws, size_t ws_size,
                              hipStream_t stream) {
    const float* x = (const float*)d_in[0];
    const float* w1 = (const float*)d_in[1];
    const float* gamma = (const float*)d_in[2];
    const float* beta = (const float*)d_in[3];
    const float* w2 = (const float*)d_in[4];
    float* out = (float*)d_out;
    float* ws = (float*)d_ws;
    unsigned short* wt = (unsigned short*)(ws + WS_WT);
    unsigned short* w2t = (unsigned short*)(ws + WS_W2T);

    hipMemsetAsync(d_ws, 0, 98304, stream);
    k_wprep<<<576, 256, 0, stream>>>(w1, wt);
    k_wprep2<<<256, 256, 0, stream>>>(w2, w2t);
    k_sums<<<B * C, 256, 0, stream>>>(x, ws);
    k_gate<<<B, 256, 0, stream>>>(ws);
    k_conv3<<<B * 256 * 2, 256, 0, stream>>>(x, wt, ws, out);
    k_scalebias<<<1, 128, 0, stream>>>(gamma, beta, ws);
    k_conv1m<<<B * 256, 256, 0, stream>>>(out, w2t, ws);
}